// Round 9
// baseline (507.713 us; speedup 1.0000x reference)
//
#include <hip/hip_runtime.h>

#define N_NODES 8192
#define FDIM 128
#define NEG_SLOPE 0.2f

typedef short short8 __attribute__((ext_vector_type(8)));
typedef float floatx16 __attribute__((ext_vector_type(16)));
typedef unsigned long long u64;

static __device__ inline unsigned fkey(float x) {
  unsigned b = __float_as_uint(x);
  return (b & 0x80000000u) ? ~b : (b | 0x80000000u);
}
static __device__ inline float fkey_dec(unsigned kk) {
  unsigned bb = (kk & 0x80000000u) ? (kk ^ 0x80000000u) : ~kk;
  return __uint_as_float(bb);
}
static __device__ inline unsigned short bf16_rn(float x) {
  unsigned u = __float_as_uint(x);
  u += 0x7fffu + ((u >> 16) & 1u);
  return (unsigned short)(u >> 16);
}

// ---- Kernel A (verified R6-R8): Wh=h@W.T; emits s1, Bj=exp(s2),
//      Dj=exp(.2 s2), s2max, S=colsum(Wh), Wh as bf16 B-fragment order ----
__global__ __launch_bounds__(256) void wh_fused_kernel(
    const float* __restrict__ h, const float* __restrict__ W,
    const float* __restrict__ a, float* __restrict__ s1g,
    float* __restrict__ Bj, float* __restrict__ Dj, float* __restrict__ S,
    unsigned* __restrict__ s2max_key, unsigned short* __restrict__ WHf) {
  __shared__ float Wt[FDIM * 129];
  __shared__ float rows[32 * 132];
  const int t = threadIdx.x;
  const int base = blockIdx.x * 32;
  for (int it = 0; it < 64; ++it) {
    int idx = t + 256 * it;
    int o = idx >> 7, k = idx & 127;
    Wt[k * 129 + o] = W[idx];
  }
  for (int it = 0; it < 16; ++it) {
    int idx = t + 256 * it;
    int r = idx >> 7, col = idx & 127;
    rows[r * 132 + col] = h[(size_t)base * FDIM + idx];
  }
  __syncthreads();
  const int c4 = (t & 31) * 4;
  const int g = t >> 5;
  float acc[4][4];
#pragma unroll
  for (int rr = 0; rr < 4; ++rr)
#pragma unroll
    for (int cc = 0; cc < 4; ++cc) acc[rr][cc] = 0.f;
  for (int k = 0; k < FDIM; ++k) {
    float4 wv = *(const float4*)&Wt[k * 129 + c4];
    float rv[4];
#pragma unroll
    for (int rr = 0; rr < 4; ++rr) rv[rr] = rows[(4 * g + rr) * 132 + k];
#pragma unroll
    for (int rr = 0; rr < 4; ++rr) {
      acc[rr][0] += rv[rr] * wv.x;
      acc[rr][1] += rv[rr] * wv.y;
      acc[rr][2] += rv[rr] * wv.z;
      acc[rr][3] += rv[rr] * wv.w;
    }
  }
  {
    float4 a1c = *(const float4*)&a[c4];
    float4 a2c = *(const float4*)&a[FDIM + c4];
    float p1[4], p2[4];
#pragma unroll
    for (int rr = 0; rr < 4; ++rr) {
      p1[rr] = acc[rr][0] * a1c.x + acc[rr][1] * a1c.y +
               acc[rr][2] * a1c.z + acc[rr][3] * a1c.w;
      p2[rr] = acc[rr][0] * a2c.x + acc[rr][1] * a2c.y +
               acc[rr][2] * a2c.z + acc[rr][3] * a2c.w;
    }
#pragma unroll
    for (int rr = 0; rr < 4; ++rr)
      for (int off = 16; off; off >>= 1) {
        p1[rr] += __shfl_down(p1[rr], off, 32);
        p2[rr] += __shfl_down(p2[rr], off, 32);
      }
    if ((t & 31) == 0) {
      unsigned kmax = 0;
#pragma unroll
      for (int rr = 0; rr < 4; ++rr) {
        int r = base + 4 * g + rr;
        s1g[r] = p1[rr];
        Bj[r] = __expf(p2[rr]);
        Dj[r] = __expf(NEG_SLOPE * p2[rr]);
        unsigned kk = fkey(p2[rr]);
        kmax = kk > kmax ? kk : kmax;
      }
      atomicMax(s2max_key, kmax);
    }
  }
  __syncthreads();
  unsigned short* hbuf = (unsigned short*)Wt;
#pragma unroll
  for (int rr = 0; rr < 4; ++rr)
#pragma unroll
    for (int cc = 0; cc < 4; ++cc) {
      int lr = 4 * g + rr;
      int n = c4 + cc;
      int idx = (((lr >> 4) * 4 + (n >> 5)) * 64 + ((lr >> 3) & 1) * 32 +
                 (n & 31)) * 8 + (lr & 7);
      hbuf[idx] = bf16_rn(acc[rr][cc]);
    }
  float4 cs = make_float4(acc[0][0] + acc[1][0] + acc[2][0] + acc[3][0],
                          acc[0][1] + acc[1][1] + acc[2][1] + acc[3][1],
                          acc[0][2] + acc[1][2] + acc[2][2] + acc[3][2],
                          acc[0][3] + acc[1][3] + acc[2][3] + acc[3][3]);
  *(float4*)&rows[g * FDIM + c4] = cs;
  __syncthreads();
  {
    const unsigned* hsrc = (const unsigned*)hbuf;
    unsigned* hdst = (unsigned*)(WHf + (size_t)base * FDIM);
    for (int q = t; q < 2048; q += 256) hdst[q] = hsrc[q];
  }
  if (t < FDIM) {
    float s = 0.f;
#pragma unroll
    for (int gg = 0; gg < 8; ++gg) s += rows[gg * FDIM + t];
    atomicAdd(&S[t], s);
  }
}

// ---- Kernel P: adj -> bitmask, memcpy-shaped. Wave covers 256 contiguous
//      floats/iter; ballot-native layout: u64 #w (w=0..3) bit l <-> col
//      offset 4l+w within the 256-chunk (matches consumer extraction). ----
__global__ __launch_bounds__(256) void pack_kernel(
    const float4* __restrict__ adj4, u64* __restrict__ bits) {
  const int t0 = blockIdx.x * 256 + threadIdx.x;
  const int lane = threadIdx.x & 63;
#pragma unroll 4
  for (int it = 0; it < 32; ++it) {
    const int idx = t0 + it * (2048 * 256);    // float4 index
    float4 v = adj4[idx];
    u64 b0 = __ballot(v.x != 0.f);
    u64 b1 = __ballot(v.y != 0.f);
    u64 b2 = __ballot(v.z != 0.f);
    u64 b3 = __ballot(v.w != 0.f);
    const int ub = (idx - lane) >> 4;          // u64 base of this 256-chunk
    if (lane < 4) {
      u64 bs = lane == 0 ? b0 : lane == 1 ? b1 : lane == 2 ? b2 : b3;
      bits[ub + lane] = bs;
    }
  }
}

// ---- Kernel B: V@Wh via bf16 MFMA, A = v_ik = mask*(q_ik - em_i) generated
//      from the global bitmask (no adj, no ballots). Block = 32 rows x 2048 K
//      (4 waves x 512 K private). Accumulates into out (=num scratch). ----
__global__ __launch_bounds__(256) void gat_mfma_kernel(
    const u64* __restrict__ bits, const unsigned short* __restrict__ WHf,
    const float* __restrict__ s1g, const float* __restrict__ Bj,
    const float* __restrict__ Dj, const unsigned* __restrict__ s2max_key,
    float* __restrict__ num, float* __restrict__ l_ws) {
  __shared__ float cred[32 * FDIM];  // 16 KB
  const int t = threadIdx.x;
  const int lane = t & 63;
  const int wave = t >> 6;
  const int lq = lane & 31, hh = lane >> 5;
  const int rowgrp = blockIdx.x >> 2;
  const int ksplit = blockIdx.x & 3;
  const int grow = rowgrp * 32;
  const int kw0 = ksplit * 2048 + wave * 512;

  for (int q = t; q < 32 * FDIM; q += 256) cred[q] = 0.f;
  __syncthreads();

  const float s2m = fkey_dec(*s2max_key);
  const float s1r = s1g[grow + lq];
  float pm = s1r + s2m;
  pm = pm > 0.f ? pm : NEG_SLOPE * pm;
  const float mr = fmaxf(pm, 0.f);
  const float emr = __expf(-mr);
  const float Ar = __expf(s1r - mr);
  const float Cr = __expf(NEG_SLOPE * s1r - mr);
  const float Tr = __expf(-s1r);  // cp: s1+s2>0 <=> Bj > Tr

  const short8* BW = (const short8*)WHf;
  const u64* myrow = bits + (size_t)(grow + lq) * (N_NODES / 64);
  floatx16 acc[4];
#pragma unroll
  for (int nt = 0; nt < 4; ++nt)
#pragma unroll
    for (int i = 0; i < 16; ++i) acc[nt][i] = 0.f;
  float lv = 0.f;

  for (int s = 0; s < 2; ++s) {
    const int c0 = kw0 + s * 256;
    const u64* bp = myrow + (c0 >> 6);
    ulonglong2 q0 = *(const ulonglong2*)bp;
    ulonglong2 q1 = *(const ulonglong2*)(bp + 2);
    const u64 ws0 = q0.x, ws1 = q0.y, ws2 = q1.x, ws3 = q1.y;
#pragma unroll 2
    for (int it = 0; it < 16; ++it) {
      const int kg = c0 + it * 16;
      const int j8 = kg + hh * 8;
      float4 b0 = *(const float4*)(Bj + j8);
      float4 b1 = *(const float4*)(Bj + j8 + 4);
      float4 d0 = *(const float4*)(Dj + j8);
      float4 d1 = *(const float4*)(Dj + j8 + 4);
      size_t fb = (size_t)(kg >> 4) * 256 + lane;
      short8 x0 = BW[fb];
      short8 x1 = BW[fb + 64];
      short8 x2 = BW[fb + 128];
      short8 x3 = BW[fb + 192];
      float bvv[8] = {b0.x, b0.y, b0.z, b0.w, b1.x, b1.y, b1.z, b1.w};
      float dvv[8] = {d0.x, d0.y, d0.z, d0.w, d1.x, d1.y, d1.z, d1.w};
      const u64 wsel[4] = {ws0, ws1, ws2, ws3};
      const int bsh = it * 4 + hh * 2;
      float vv[8];
#pragma unroll
      for (int e = 0; e < 8; ++e) {
        unsigned bit = (unsigned)(wsel[e & 3] >> (bsh + (e >> 2))) & 1u;
        bool cp = bvv[e] > Tr;
        float q = (cp ? Ar : Cr) * (cp ? bvv[e] : dvv[e]);
        float v = bit ? (q - emr) : 0.f;
        vv[e] = v;
        lv += v;
      }
      union { uint4 u; short8 s8; } pk;
      pk.u.x = (unsigned)bf16_rn(vv[0]) | ((unsigned)bf16_rn(vv[1]) << 16);
      pk.u.y = (unsigned)bf16_rn(vv[2]) | ((unsigned)bf16_rn(vv[3]) << 16);
      pk.u.z = (unsigned)bf16_rn(vv[4]) | ((unsigned)bf16_rn(vv[5]) << 16);
      pk.u.w = (unsigned)bf16_rn(vv[6]) | ((unsigned)bf16_rn(vv[7]) << 16);
      short8 af = pk.s8;
      acc[0] = __builtin_amdgcn_mfma_f32_32x32x16_bf16(af, x0, acc[0], 0, 0, 0);
      acc[1] = __builtin_amdgcn_mfma_f32_32x32x16_bf16(af, x1, acc[1], 0, 0, 0);
      acc[2] = __builtin_amdgcn_mfma_f32_32x32x16_bf16(af, x2, acc[2], 0, 0, 0);
      acc[3] = __builtin_amdgcn_mfma_f32_32x32x16_bf16(af, x3, acc[3], 0, 0, 0);
    }
  }
  float lvt = lv + __shfl_xor(lv, 32);
  if (lane < 32) atomicAdd(&l_ws[grow + lq], lvt);
  // C layout (verified R6-R8): col = nt*32+lq, row = (reg&3)+8*(reg>>2)+4*hh
#pragma unroll
  for (int reg = 0; reg < 16; ++reg) {
    const int r = (reg & 3) + 8 * (reg >> 2) + 4 * hh;
#pragma unroll
    for (int nt = 0; nt < 4; ++nt)
      atomicAdd(&cred[r * FDIM + nt * 32 + lq], acc[nt][reg]);
  }
  __syncthreads();
  for (int q = t; q < 32 * FDIM; q += 256)
    atomicAdd(&num[(size_t)(grow + (q >> 7)) * FDIM + (q & 127)], cred[q]);
}

// ---- Kernel C: out = (num + em*S) / (N*em + l)   (in-place on out) ----
__global__ __launch_bounds__(256) void norm_kernel(
    float* __restrict__ numout, const float* __restrict__ l_ws,
    const float* __restrict__ s1g, const unsigned* __restrict__ s2max_key,
    const float* __restrict__ S) {
  const int idx = blockIdx.x * 256 + threadIdx.x;  // float4 index
  const int row = idx >> 5;
  const float s2m = fkey_dec(*s2max_key);
  float s1r = s1g[row];
  float pm = s1r + s2m;
  pm = pm > 0.f ? pm : NEG_SLOPE * pm;
  float mr = fmaxf(pm, 0.f);
  float em = __expf(-mr);
  float l = (float)N_NODES * em + l_ws[row];
  float inv = 1.f / l;
  float4 nv = ((float4*)numout)[idx];
  float4 Sv = ((const float4*)S)[idx & 31];
  ((float4*)numout)[idx] = make_float4((nv.x + em * Sv.x) * inv,
                                       (nv.y + em * Sv.y) * inv,
                                       (nv.z + em * Sv.z) * inv,
                                       (nv.w + em * Sv.w) * inv);
}

extern "C" void kernel_launch(void* const* d_in, const int* in_sizes, int n_in,
                              void* d_out, int out_size, void* d_ws, size_t ws_size,
                              hipStream_t stream) {
  const float* h   = (const float*)d_in[0];
  const float* adj = (const float*)d_in[1];
  const float* W   = (const float*)d_in[2];
  const float* a   = (const float*)d_in[3];
  float* out = (float*)d_out;  // doubles as num accumulator (4 MB)
  // ws (~10.2 MB): bits[1M u64] | WHf[1M u16] | l[8K f] | S[128 f]
  //                | key[4 u32] | s1[8K f] | Bj[8K f] | Dj[8K f]
  u64* bits = (u64*)d_ws;
  unsigned short* WHf = (unsigned short*)(bits + (size_t)(N_NODES / 64) * N_NODES);
  float* l_ws = (float*)(WHf + (size_t)N_NODES * FDIM);
  float* S = l_ws + N_NODES;
  unsigned* key = (unsigned*)(S + FDIM);
  float* s1 = (float*)(key + 4);
  float* Bj = s1 + N_NODES;
  float* Dj = Bj + N_NODES;

  hipMemsetAsync(out, 0, (size_t)N_NODES * FDIM * sizeof(float), stream);
  hipMemsetAsync(l_ws, 0, (N_NODES + FDIM + 4) * sizeof(float), stream);
  hipLaunchKernelGGL(pack_kernel, dim3(2048), dim3(256), 0, stream,
                     (const float4*)adj, bits);
  hipLaunchKernelGGL(wh_fused_kernel, dim3(N_NODES / 32), dim3(256), 0, stream,
                     h, W, a, s1, Bj, Dj, S, key, WHf);
  hipLaunchKernelGGL(gat_mfma_kernel, dim3(1024), dim3(256), 0, stream,
                     bits, WHf, s1, Bj, Dj, key, out, l_ws);
  hipLaunchKernelGGL(norm_kernel, dim3(N_NODES * FDIM / 4 / 256), dim3(256), 0,
                     stream, out, l_ws, s1, key, S);
}